// Round 1
// baseline (95.204 us; speedup 1.0000x reference)
//
#include <hip/hip_runtime.h>
#include <math.h>

#define EPSF 1e-8f

constexpr int B = 512;
constexpr int F = 256;
constexpr int NF4 = F / 4;        // 64 float4 per row
constexpr int NTHREADS = 256;

// One block per output row i.
__global__ __launch_bounds__(256) void hinge_rows(
    const int* __restrict__ ids,
    const float* __restrict__ feats,
    float* __restrict__ rowloss,
    int* __restrict__ rowvalid)
{
    const int i    = blockIdx.x;
    const int tid  = threadIdx.x;
    const int lane = tid & 63;
    const int wid  = tid >> 6;

    __shared__ float4 sfi[NF4];     // feats row i
    __shared__ float  cosr[B];      // cos(i, j) for all j
    __shared__ int    ddr[B];       // sum |ids[i]-ids[j]| for all j
    __shared__ float  part_s[4];
    __shared__ float  part_n[4];

    if (tid < NF4) sfi[tid] = ((const float4*)(feats + (size_t)i * F))[tid];
    __syncthreads();

    // norm of row i (redundant per-thread compute; LDS broadcast reads, cheap)
    float ssi = 0.f;
    #pragma unroll
    for (int f = 0; f < NF4; ++f) {
        float4 u = sfi[f];
        ssi += u.x*u.x + u.y*u.y + u.z*u.z + u.w*u.w;
    }
    const float ni = fmaxf(sqrtf(ssi + EPSF), EPSF);

    // Phase 1a: cos(i, j) for all j — one wave per j-row, fully coalesced
    const float4 u = sfi[lane];
    for (int r = 0; r < B / 4; ++r) {
        const int j = r * 4 + wid;
        float4 v = ((const float4*)(feats + (size_t)j * F))[lane];
        float dot = u.x*v.x + u.y*v.y + u.z*v.z + u.w*v.w;
        float ssj = v.x*v.x + v.y*v.y + v.z*v.z + v.w*v.w;
        #pragma unroll
        for (int off = 32; off > 0; off >>= 1) {
            dot += __shfl_down(dot, off);
            ssj += __shfl_down(ssj, off);
        }
        if (lane == 0) {
            float nj = fmaxf(sqrtf(ssj + EPSF), EPSF);
            cosr[j] = dot / (ni * nj);
        }
    }

    // Phase 1b: id-distance row (coalesced int4 reads)
    const int4 idi = ((const int4*)ids)[i];
    for (int jj = 0; jj < B / NTHREADS; ++jj) {
        int j = tid + jj * NTHREADS;
        int4 idj = ((const int4*)ids)[j];
        int d = abs(idi.x - idj.x) + abs(idi.y - idj.y)
              + abs(idi.z - idj.z) + abs(idi.w - idj.w);
        ddr[j] = d;
    }
    __syncthreads();

    // Each thread owns negatives k = tid and tid+256 (d>0 excludes k==i automatically)
    const int d0 = ddr[tid], d1 = ddr[tid + NTHREADS];
    const bool m0 = d0 > 0, m1 = d1 > 0;
    const float b0 = 0.15f * (float)d0 + cosr[tid];
    const float b1 = 0.15f * (float)d1 + cosr[tid + NTHREADS];

    float s   = 0.f;
    float ndf = (m0 ? 1.f : 0.f) + (m1 ? 1.f : 0.f);
    // Deterministic fixed-order sweep over positives j (wave-uniform skip)
    for (int j = 0; j < B; ++j) {
        if (ddr[j] == 0 && j != i) {
            float aj = cosr[j];
            if (m0) s += fmaxf(0.f, b0 - aj);
            if (m1) s += fmaxf(0.f, b1 - aj);
        }
    }

    // block reduce s (pair-hinge sum) and ndf (negative count)
    #pragma unroll
    for (int off = 32; off > 0; off >>= 1) {
        s   += __shfl_down(s, off);
        ndf += __shfl_down(ndf, off);
    }
    if (lane == 0) { part_s[wid] = s; part_n[wid] = ndf; }
    __syncthreads();
    if (tid == 0) {
        float tot = part_s[0] + part_s[1] + part_s[2] + part_s[3];
        float nd  = part_n[0] + part_n[1] + part_n[2] + part_n[3];
        float ns  = 511.f - nd;        // every j != i is either sim or dif
        float cnt = ns * nd;
        rowloss[i]  = (cnt > 0.f) ? tot / cnt : 0.f;
        rowvalid[i] = (cnt > 0.f) ? 1 : 0;
    }
}

__global__ __launch_bounds__(256) void finalize_kernel(
    const float* __restrict__ rowloss,
    const int* __restrict__ rowvalid,
    float* __restrict__ out)
{
    const int tid  = threadIdx.x;
    const int lane = tid & 63;
    const int wid  = tid >> 6;
    __shared__ float sb[4], vb[4];

    float s = rowloss[tid] + rowloss[tid + NTHREADS];
    float v = (float)(rowvalid[tid] + rowvalid[tid + NTHREADS]);
    #pragma unroll
    for (int off = 32; off > 0; off >>= 1) {
        s += __shfl_down(s, off);
        v += __shfl_down(v, off);
    }
    if (lane == 0) { sb[wid] = s; vb[wid] = v; }
    __syncthreads();
    if (tid == 0) {
        float ts = sb[0] + sb[1] + sb[2] + sb[3];
        float tv = vb[0] + vb[1] + vb[2] + vb[3];
        out[0] = ts / fmaxf(tv, 1.f);
    }
}

extern "C" void kernel_launch(void* const* d_in, const int* in_sizes, int n_in,
                              void* d_out, int out_size, void* d_ws, size_t ws_size,
                              hipStream_t stream) {
    const int*   ids   = (const int*)d_in[0];
    const float* feats = (const float*)d_in[1];
    float* out      = (float*)d_out;
    float* rowloss  = (float*)d_ws;
    int*   rowvalid = (int*)((char*)d_ws + B * sizeof(float));

    hipLaunchKernelGGL(hinge_rows, dim3(B), dim3(NTHREADS), 0, stream,
                       ids, feats, rowloss, rowvalid);
    hipLaunchKernelGGL(finalize_kernel, dim3(1), dim3(NTHREADS), 0, stream,
                       rowloss, rowvalid, out);
}

// Round 2
// 22.749 us; speedup vs baseline: 4.1849x; 4.1849x over previous
//
#include <hip/hip_runtime.h>
#include <math.h>

#define EPSF 1e-8f

constexpr int B = 512;
constexpr int F = 256;
constexpr int TS = 16;            // cos tile size
constexpr int LDP = F + 4;        // padded LDS row (260 floats) — breaks bank alias
constexpr int NTHREADS = 256;

// ---------------- kernel 1: inverse norms, one wave per row ----------------
__global__ __launch_bounds__(256) void norms_kernel(
    const float* __restrict__ feats, float* __restrict__ invn)
{
    const int tid  = threadIdx.x;
    const int lane = tid & 63;
    const int wid  = tid >> 6;
    const int row  = blockIdx.x * 4 + wid;   // 128 blocks * 4 waves = 512 rows

    float4 v = ((const float4*)(feats + (size_t)row * F))[lane]; // 64 lanes * 4 = 256
    float ss = v.x*v.x + v.y*v.y + v.z*v.z + v.w*v.w;
    #pragma unroll
    for (int off = 32; off > 0; off >>= 1) ss += __shfl_down(ss, off);
    if (lane == 0) invn[row] = 1.f / fmaxf(sqrtf(ss + EPSF), EPSF);
}

// ---------------- kernel 2: cos matrix, 16x16 tile per block ----------------
__global__ __launch_bounds__(256) void cos_kernel(
    const float* __restrict__ feats, const float* __restrict__ invn,
    float* __restrict__ cosm)
{
    __shared__ float As[TS][LDP];
    __shared__ float Bs[TS][LDP];

    const int it = blockIdx.y, jt = blockIdx.x;
    const int tid = threadIdx.x;
    const int r = tid >> 4, c = tid & 15;

    const float4* Ag = (const float4*)(feats + (size_t)(it * TS + r) * F);
    const float4* Bg = (const float4*)(feats + (size_t)(jt * TS + r) * F);
    #pragma unroll
    for (int q = 0; q < 4; ++q) {                 // 16 threads/row * 4 float4 = 64
        float4 a = Ag[c + 16 * q];
        *(float4*)&As[r][(c + 16 * q) * 4] = a;
        float4 b = Bg[c + 16 * q];
        *(float4*)&Bs[r][(c + 16 * q) * 4] = b;
    }
    __syncthreads();

    // thread (ty,tx) computes cos(it*16+ty, jt*16+tx)
    const int ty = tid >> 4, tx = tid & 15;
    float acc = 0.f;
    #pragma unroll 8
    for (int k4 = 0; k4 < F / 4; ++k4) {
        float4 a = *(const float4*)&As[ty][k4 * 4];   // 16-lane broadcast, conflict-free
        float4 b = *(const float4*)&Bs[tx][k4 * 4];   // padded stride -> <=2-way (free)
        acc += a.x*b.x + a.y*b.y + a.z*b.z + a.w*b.w;
    }
    const int gi = it * TS + ty, gj = jt * TS + tx;
    cosm[(size_t)gi * B + gj] = acc * invn[gi] * invn[gj];
}

// ---------------- kernel 3: per-row hinge sums ----------------
__global__ __launch_bounds__(256) void rows_kernel(
    const int* __restrict__ ids, const float* __restrict__ cosm,
    float* __restrict__ rowloss, int* __restrict__ rowvalid)
{
    const int i    = blockIdx.x;
    const int tid  = threadIdx.x;
    const int lane = tid & 63;
    const int wid  = tid >> 6;

    __shared__ int   dd[B];
    __shared__ float vals[B];                // compacted cos[i][j] for j in sim(i)
    __shared__ unsigned long long cmask[8];
    __shared__ int   coff[9];
    __shared__ float part_s[4], part_n[4];

    // id-distance row (coalesced int4)
    const int4 idi = ((const int4*)ids)[i];
    #pragma unroll
    for (int jj = 0; jj < B / NTHREADS; ++jj) {
        int j = tid + jj * NTHREADS;
        int4 idj = ((const int4*)ids)[j];
        dd[j] = abs(idi.x - idj.x) + abs(idi.y - idj.y)
              + abs(idi.z - idj.z) + abs(idi.w - idj.w);
    }
    __syncthreads();

    // deterministic ballot-compaction of sim set {j : dd[j]==0, j!=i}
    #pragma unroll
    for (int cc = 0; cc < 2; ++cc) {
        int chunk = wid * 2 + cc;
        int j = chunk * 64 + lane;
        bool pred = (dd[j] == 0) && (j != i);
        unsigned long long m = __ballot(pred);
        if (lane == 0) { cmask[chunk] = m; }
    }
    __syncthreads();
    if (tid == 0) {
        int acc = 0;
        #pragma unroll
        for (int cch = 0; cch < 8; ++cch) {
            coff[cch] = acc;
            acc += (int)__popcll(cmask[cch]);
        }
        coff[8] = acc;
    }
    __syncthreads();
    #pragma unroll
    for (int cc = 0; cc < 2; ++cc) {
        int chunk = wid * 2 + cc;
        int j = chunk * 64 + lane;
        unsigned long long m = cmask[chunk];
        if ((m >> lane) & 1ull) {
            int pos = coff[chunk] +
                      (int)__popcll(m & ((1ull << lane) - 1ull));
            vals[pos] = cosm[(size_t)i * B + j];
        }
    }
    __syncthreads();

    const int ns = coff[8];

    // each thread owns negatives k = tid, tid+256 (dd>0 excludes k==i)
    const int d0 = dd[tid], d1 = dd[tid + NTHREADS];
    const bool m0 = d0 > 0, m1 = d1 > 0;
    const float c0 = cosm[(size_t)i * B + tid];
    const float c1 = cosm[(size_t)i * B + tid + NTHREADS];
    const float b0 = 0.15f * (float)d0 + c0;
    const float b1 = 0.15f * (float)d1 + c1;

    float s   = 0.f;
    float ndf = (m0 ? 1.f : 0.f) + (m1 ? 1.f : 0.f);
    for (int t = 0; t < ns; ++t) {           // ~31 iters, broadcast LDS reads
        float a = vals[t];
        if (m0) s += fmaxf(0.f, b0 - a);
        if (m1) s += fmaxf(0.f, b1 - a);
    }

    #pragma unroll
    for (int off = 32; off > 0; off >>= 1) {
        s   += __shfl_down(s, off);
        ndf += __shfl_down(ndf, off);
    }
    if (lane == 0) { part_s[wid] = s; part_n[wid] = ndf; }
    __syncthreads();
    if (tid == 0) {
        float tot = part_s[0] + part_s[1] + part_s[2] + part_s[3];
        float nd  = part_n[0] + part_n[1] + part_n[2] + part_n[3];
        float cnt = (float)ns * nd;
        rowloss[i]  = (cnt > 0.f) ? tot / cnt : 0.f;
        rowvalid[i] = (cnt > 0.f) ? 1 : 0;
    }
}

// ---------------- kernel 4: final mean over valid rows ----------------
__global__ __launch_bounds__(256) void finalize_kernel(
    const float* __restrict__ rowloss, const int* __restrict__ rowvalid,
    float* __restrict__ out)
{
    const int tid  = threadIdx.x;
    const int lane = tid & 63;
    const int wid  = tid >> 6;
    __shared__ float sb[4], vb[4];

    float s = rowloss[tid] + rowloss[tid + NTHREADS];
    float v = (float)(rowvalid[tid] + rowvalid[tid + NTHREADS]);
    #pragma unroll
    for (int off = 32; off > 0; off >>= 1) {
        s += __shfl_down(s, off);
        v += __shfl_down(v, off);
    }
    if (lane == 0) { sb[wid] = s; vb[wid] = v; }
    __syncthreads();
    if (tid == 0) {
        float ts = sb[0] + sb[1] + sb[2] + sb[3];
        float tv = vb[0] + vb[1] + vb[2] + vb[3];
        out[0] = ts / fmaxf(tv, 1.f);
    }
}

extern "C" void kernel_launch(void* const* d_in, const int* in_sizes, int n_in,
                              void* d_out, int out_size, void* d_ws, size_t ws_size,
                              hipStream_t stream) {
    const int*   ids   = (const int*)d_in[0];
    const float* feats = (const float*)d_in[1];
    float* out = (float*)d_out;

    char* ws = (char*)d_ws;
    float* cosm     = (float*)ws;                              // 512*512*4 = 1 MB
    float* invn     = (float*)(ws + (size_t)B * B * 4);        // 2 KB
    float* rowloss  = (float*)(ws + (size_t)B * B * 4 + 2048); // 2 KB
    int*   rowvalid = (int*)  (ws + (size_t)B * B * 4 + 4096); // 2 KB

    hipLaunchKernelGGL(norms_kernel, dim3(B / 4), dim3(NTHREADS), 0, stream,
                       feats, invn);
    hipLaunchKernelGGL(cos_kernel, dim3(B / TS, B / TS), dim3(NTHREADS), 0, stream,
                       feats, invn, cosm);
    hipLaunchKernelGGL(rows_kernel, dim3(B), dim3(NTHREADS), 0, stream,
                       ids, cosm, rowloss, rowvalid);
    hipLaunchKernelGGL(finalize_kernel, dim3(1), dim3(NTHREADS), 0, stream,
                       rowloss, rowvalid, out);
}